// Round 5
// baseline (661.994 us; speedup 1.0000x reference)
//
#include <hip/hip_runtime.h>

#define DEG 16
#define DD  128
#define KT  10      // template nodes
#define TT  10      // templates
#define MM  17      // m = DEG+1
#define NPB 4       // nodes per block
#define THREADS 640 // 10 waves: wave w <-> template w

#if __has_builtin(__builtin_amdgcn_exp2f)
#define FEXP2(x) __builtin_amdgcn_exp2f(x)
#else
#define FEXP2(x) exp2f(x)
#endif

#if __has_builtin(__builtin_amdgcn_rcpf)
#define FRCP(x) __builtin_amdgcn_rcpf(x)
#else
#define FRCP(x) (1.0f / (x))
#endif

#if __has_builtin(__builtin_amdgcn_logf)
#define FLOG2(x) __builtin_amdgcn_logf(x)
#else
#define FLOG2(x) log2f(x)
#endif

// (1/EPS)*log2(e), EPS = 0.5
#define TWO_LOG2E  2.8853900817779268f
// (0.5/EPS)*log2(e) = log2(e)
#define HALF_LOG2E 1.4426950408889634f
#define LN2        0.6931471805599453f

typedef float v2f __attribute__((ext_vector_type(2)));

__device__ __forceinline__ v2f make2(float s) { v2f r; r.x = s; r.y = s; return r; }

// ---- pure-VALU cross-lane add within each 16-lane row ----
template <int CTRL>
__device__ __forceinline__ float dpp_add(float x) {
    union { float f; int i; } a, b;
    a.f = x;
    b.i = __builtin_amdgcn_update_dpp(0, a.i, CTRL, 0xF, 0xF, true);
    return x + b.f;
}
// full 16-lane sum, broadcast to all 16 lanes
__device__ __forceinline__ float sum16(float t) {
    t = dpp_add<0xB1>(t);   // quad_perm xor 1
    t = dpp_add<0x4E>(t);   // quad_perm xor 2
    t = dpp_add<0x124>(t);  // row_ror:4
    t = dpp_add<0x128>(t);  // row_ror:8
    return t;
}

__global__ __launch_bounds__(THREADS, 2) void ltfgw_kernel(
    const float* __restrict__ x,      // [N,128]
    const int*   __restrict__ ei,     // edge_index[0], [N*DEG]
    const float* __restrict__ tmpl,   // [T,K,K]
    const float* __restrict__ tf,     // [T,K,128]
    float* __restrict__ out,          // [N,T]
    int N)
{
    constexpr int SLAB = MM * DD + 4;
    __shared__ float sFi[NPB * SLAB];
    __shared__ float sNrm[NPB][MM];

    const int tid = threadIdx.x;
    const int b0  = blockIdx.x * NPB;

    // ---- stage Fi
    {
        const int kq = tid & 31;
        for (int r = tid >> 5; r < NPB * MM; r += (THREADS >> 5)) {
            int p = r / MM, j = r % MM;
            int node = b0 + p;
            if (node < N) {
                int src = (j == 0) ? node : ei[node * DEG + (j - 1)];
                float4 v = *(const float4*)(x + (size_t)src * DD + kq * 4);
                *(float4*)(&sFi[p * SLAB + j * DD + kq * 4]) = v;
            }
        }
    }
    __syncthreads();

    // ---- per-row squared norms
    if (tid < NPB * MM) {
        int p = tid / MM, j = tid % MM;
        const float* row = &sFi[p * SLAB + j * DD];
        float acc = 0.f;
        for (int kidx = 0; kidx < 32; ++kidx) {
            int kq2 = (kidx + tid) & 31;
            float4 v = *(const float4*)(row + kq2 * 4);
            acc += v.x * v.x + v.y * v.y + v.z * v.z + v.w * v.w;
        }
        sNrm[p][j] = acc;
    }
    __syncthreads();

    const int w    = tid >> 6;         // template index
    const int lane = tid & 63;
    const int p    = lane >> 4;        // node sub-slot 0..3
    const int c    = lane & 15;        // template column (active if <10)
    const bool act = (c < KT);
    const int node = b0 + p;
    const int cc   = act ? c : 0;

    // ---- Ct row + ct2q
    float CtRow[KT];
    float ct2q = 0.f;
#pragma unroll
    for (int jj = 0; jj < KT; ++jj) {
        CtRow[jj] = tmpl[(w * KT + cc) * KT + jj];
        ct2q += CtRow[jj] * CtRow[jj];
    }
    ct2q *= (1.f / KT);

    // ---- feature-cost dots (packed f32 pairs -> v_pk_fma_f32)
    v2f dot2[MM];
#pragma unroll
    for (int j = 0; j < MM; ++j) dot2[j] = make2(0.f);
    v2f nft2 = make2(0.f);
    const float* ftrow = tf + (size_t)(w * KT + cc) * DD;
    for (int kk = 0; kk < DD; kk += 4) {
        float4 f4 = *(const float4*)(ftrow + kk);
        v2f fa; fa.x = f4.x; fa.y = f4.y;
        v2f fb; fb.x = f4.z; fb.y = f4.w;
        nft2 += fa * fa;
        nft2 += fb * fb;
#pragma unroll
        for (int j = 0; j < MM; ++j) {
            float4 a4 = *(const float4*)(&sFi[p * SLAB + j * DD + kk]);
            v2f aa; aa.x = a4.x; aa.y = a4.y;
            v2f ab; ab.x = a4.z; ab.y = a4.w;
            dot2[j] += aa * fa;
            dot2[j] += ab * fb;
        }
    }
    float nft = nft2.x + nft2.y;

    // E_M[j] = exp2(-log2e * Mc[j]); Mc recovered via log2 in the epilogue
    v2f  E_M2[8];
    float E_Ml;
#pragma unroll
    for (int jj = 0; jj < 8; ++jj) {
        float d0 = dot2[2 * jj].x + dot2[2 * jj].y;
        float d1 = dot2[2 * jj + 1].x + dot2[2 * jj + 1].y;
        float M0 = (sNrm[p][2 * jj]     + nft - 2.f * d0) * (1.f / DD);
        float M1 = (sNrm[p][2 * jj + 1] + nft - 2.f * d1) * (1.f / DD);
        E_M2[jj].x = FEXP2(-HALF_LOG2E * M0);
        E_M2[jj].y = FEXP2(-HALF_LOG2E * M1);
    }
    {
        float dl = dot2[16].x + dot2[16].y;
        float Ml = (sNrm[p][16] + nft - 2.f * dl) * (1.f / DD);
        E_Ml = FEXP2(-HALF_LOG2E * Ml);
    }

    // ---- scaled-domain proximal Sinkhorn
    const float pw = 1.f / MM;
    const float QP = 17.f / 10.f;      // qw / pw
    const int gbase = lane & ~15;

    v2f Tp2[8], eK2[8], u2[8];
    float Tpl, eKl, ul;
    const float tpinit = act ? (1.f / (MM * KT)) : 0.f;
#pragma unroll
    for (int jj = 0; jj < 8; ++jj) Tp2[jj] = make2(tpinit);
    Tpl = tpinit;

    float obj = 0.f;

// One Sinkhorn iteration. NEWTON=0: exact rcp seed; NEWTON=1: 1-step
// Newton refine of u from previous iteration (t drifts only a few %
// after iter 2; clamp guards positivity if it ever overshoots).
#define SINK_ITER(NEWTON)                                                   \
    {                                                                       \
        v2f cacc = make2(0.f);                                              \
        _Pragma("unroll")                                                   \
        for (int jj = 0; jj < 8; ++jj) {                                    \
            v2f prod = eK2[jj] * v;                                         \
            v2f t2; t2.x = sum16(prod.x); t2.y = sum16(prod.y);             \
            if (NEWTON) {                                                   \
                v2f corr = 2.0f - t2 * u2[jj];                              \
                corr = __builtin_elementwise_max(corr, make2(0.0625f));     \
                u2[jj] = u2[jj] * corr;                                     \
            } else {                                                        \
                u2[jj].x = FRCP(t2.x); u2[jj].y = FRCP(t2.y);               \
            }                                                               \
            cacc += eK2[jj] * u2[jj];                                       \
        }                                                                   \
        float tl = sum16(eKl * v);                                          \
        if (NEWTON) { float cl = fmaxf(2.f - tl * ul, 0.0625f); ul *= cl; } \
        else ul = FRCP(tl);                                                 \
        float colacc = cacc.x + cacc.y + eKl * ul;                          \
        v = act ? QP * FRCP(colacc) : 0.f;                                  \
    }

#pragma unroll 1
    for (int outer = 0; outer <= 5; ++outer) {
        v2f cs2 = Tp2[0];
#pragma unroll
        for (int jj = 1; jj < 8; ++jj) cs2 += Tp2[jj];
        float colsum = cs2.x + cs2.y + Tpl;
        float t0 = Tp2[0].x;
        float s  = colsum - t0;

        // (Ci@Tp@Ct^T): row0 -> Ct.s ; rows>=1 -> Ct.Tp[0,:]
        float Cs = 0.f, C0 = 0.f;
#pragma unroll
        for (int jj = 0; jj < KT; ++jj) {
            float sv = __shfl(s,  gbase + jj, 64);
            float tv = __shfl(t0, gbase + jj, 64);
            Cs += CtRow[jj] * sv;
            C0 += CtRow[jj] * tv;
        }

        float gw0 = (16.f / 17.f) + ct2q - 2.f * Cs;   // row 0
        float gw1 = (1.f / 17.f)  + ct2q - 2.f * C0;   // rows 1..16

        if (outer == 5) {
            v2f gwv0; gwv0.x = 0.5f * gw0; gwv0.y = 0.5f * gw1;
            v2f gwv = make2(0.5f * gw1);
            v2f ob2 = make2(0.f);
#pragma unroll
            for (int jj = 0; jj < 8; ++jj) {
                v2f Mc2;
                Mc2.x = -LN2 * FLOG2(E_M2[jj].x);
                Mc2.y = -LN2 * FLOG2(E_M2[jj].y);
                ob2 += Tp2[jj] * (0.5f * Mc2 + ((jj == 0) ? gwv0 : gwv));
            }
            float Mcl = -LN2 * FLOG2(E_Ml);
            obj = ob2.x + ob2.y + Tpl * (0.5f * Mcl + 0.5f * gw1);
            break;
        }

        // mirror step: eK = Tp * E_M * exp(-gw/EPS)
        float G0 = FEXP2(-TWO_LOG2E * gw0);
        float G1 = FEXP2(-TWO_LOG2E * gw1);
        {
            v2f g01; g01.x = G0; g01.y = G1;
            eK2[0] = Tp2[0] * E_M2[0] * g01;
#pragma unroll
            for (int jj = 1; jj < 8; ++jj) eK2[jj] = Tp2[jj] * E_M2[jj] * G1;
            eKl = Tpl * E_Ml * G1;
        }

        // 10 Sinkhorn iterations: 2 exact-rcp seeds, 8 Newton-refined
        float v = 1.f;
        SINK_ITER(0)
        SINK_ITER(0)
#pragma unroll 1
        for (int it = 2; it < 10; ++it) SINK_ITER(1)

        float pv = pw * v;
#pragma unroll
        for (int jj = 0; jj < 8; ++jj) Tp2[jj] = eK2[jj] * u2[jj] * pv;
        Tpl = eKl * ul * pv;
    }

    // sum over the 16-lane group (inactive lanes contribute exact 0)
    obj = sum16(obj);

    if (act && c == 0 && node < N) out[node * TT + w] = obj;
}

extern "C" void kernel_launch(void* const* d_in, const int* in_sizes, int n_in,
                              void* d_out, int out_size, void* d_ws, size_t ws_size,
                              hipStream_t stream) {
    const float* x    = (const float*)d_in[0];
    const int*   ei   = (const int*)d_in[1];
    const float* tmpl = (const float*)d_in[2];
    const float* tf   = (const float*)d_in[3];
    float* out = (float*)d_out;
    int N = in_sizes[0] / DD;
    int grid = (N + NPB - 1) / NPB;
    hipLaunchKernelGGL(ltfgw_kernel, dim3(grid), dim3(THREADS), 0, stream,
                       x, ei, tmpl, tf, out, N);
}